// Round 1
// baseline (133.992 us; speedup 1.0000x reference)
//
#include <hip/hip_runtime.h>
#include <hip/hip_bf16.h>
#include <math.h>

#define TOKENS 16384
#define SEQLEN 2048
#define NCHUNK 64
#define LCHUNK 32

typedef __attribute__((ext_vector_type(8))) short bf16x8;
typedef __attribute__((ext_vector_type(8))) unsigned short u16x8;
typedef __attribute__((ext_vector_type(4))) float f32x4;

__device__ inline unsigned short f2bf(float f) {          // RNE fp32->bf16
    unsigned u = __float_as_uint(f);
    return (unsigned short)((u + 0x7FFF + ((u >> 16) & 1)) >> 16);
}
__device__ inline float bf2f(unsigned short b) {
    return __uint_as_float((unsigned)b << 16);
}
__device__ inline f32x4 mfma16(bf16x8 a, bf16x8 b, f32x4 c) {
    return __builtin_amdgcn_mfma_f32_16x16x32_bf16(a, b, c, 0, 0, 0);
}

// ---------------- K0: weight prep only (proj0 moved into k_gemm_in) ---------
__global__ void k_prep2(const float* __restrict__ ipw, const float* __restrict__ opw,
                        const float* __restrict__ mlw,
                        const float* __restrict__ xpw, const float* __restrict__ dtw,
                        __hip_bfloat16* __restrict__ wi, __hip_bfloat16* __restrict__ wo,
                        __hip_bfloat16* __restrict__ wm, __hip_bfloat16* __restrict__ Wx) {
    int i = blockIdx.x * 256 + threadIdx.x;
    if (i < 65536) {
        wi[i] = __float2bfloat16(ipw[i]);
    } else if (i < 98304) {
        wo[i-65536] = __float2bfloat16(opw[i-65536]);
    } else if (i < 114688) {
        wm[i-98304] = __float2bfloat16(mlw[i-98304]);
    } else {
        int j = i - 114688;                        // Wx[384][256]
        int n = j >> 8, k = j & 255;
        float v = 0.f;
        if (n < 256) {
            #pragma unroll
            for (int jj = 0; jj < 8; ++jj) v = fmaf(dtw[n*8+jj], xpw[jj*256+k], v);
        } else if (n < 272) {
            v = xpw[(n-248)*256 + k];
        }
        Wx[j] = __float2bfloat16(v);
    }
}

// ---------------- K1: fused proj0+tanh -> in_proj GEMM -> split xc/z --------
// A-tile (32 tok x 128) computed on the fly from x/p0w; K=128, N=512.
__global__ __launch_bounds__(256) void k_gemm_in(
    const float* __restrict__ x, const float* __restrict__ p0w,
    const float* __restrict__ p0b,
    const __hip_bfloat16* __restrict__ W,     // [512][128] bf16
    __hip_bfloat16* __restrict__ xcb, __hip_bfloat16* __restrict__ zb)
{
    constexpr int K_ = 128, LDT = K_ + 16;
    __shared__ __hip_bfloat16 Al[32][LDT];
    __shared__ __hip_bfloat16 Wl[64][LDT];
    __shared__ float sx[32][3];
    int tid = threadIdx.x;
    int m0 = blockIdx.x * 32, n0 = blockIdx.y * 64;
    const char* gW = (const char*)(W + (size_t)n0 * K_);
    float4 wv[4];
    #pragma unroll
    for (int c = 0; c < 4; ++c) wv[c] = *(const float4*)(gW + c*4096 + tid*16);
    if (tid < 96) sx[tid/3][tid%3] = x[(size_t)(m0 + tid/3)*3 + tid%3];
    __syncthreads();
    {
        int col = tid & 127;
        float w0 = p0w[col*3+0], w1 = p0w[col*3+1], w2 = p0w[col*3+2];
        float b  = p0b[col];
        int r0 = tid >> 7;
        #pragma unroll
        for (int it = 0; it < 16; ++it) {
            int row = r0 + it*2;
            float v = b + sx[row][0]*w0 + sx[row][1]*w1 + sx[row][2]*w2;
            Al[row][col] = __float2bfloat16(tanhf(v));
        }
    }
    #pragma unroll
    for (int c = 0; c < 4; ++c) {
        int flat = c*4096 + tid*16;
        *(float4*)&Wl[flat >> 8][(flat & 255) >> 1] = wv[c];
    }
    __syncthreads();
    int ln = tid & 63, w = tid >> 6;
    int r = ln & 15, q = ln >> 4;
    f32x4 acc0 = (f32x4){0.f,0.f,0.f,0.f};
    f32x4 acc1 = (f32x4){0.f,0.f,0.f,0.f};
    const __hip_bfloat16* wrow  = &Wl[w*16 + r][q*8];
    const __hip_bfloat16* arow0 = &Al[r][q*8];
    const __hip_bfloat16* arow1 = &Al[16 + r][q*8];
    #pragma unroll
    for (int kk = 0; kk < K_/32; ++kk) {
        bf16x8 wf = *(const bf16x8*)(wrow  + kk*32);
        bf16x8 a0 = *(const bf16x8*)(arow0 + kk*32);
        bf16x8 a1 = *(const bf16x8*)(arow1 + kk*32);
        acc0 = mfma16(a0, wf, acc0);
        acc1 = mfma16(a1, wf, acc1);
    }
    int col = n0 + w*16 + r;
    #pragma unroll
    for (int mi = 0; mi < 2; ++mi) {
        #pragma unroll
        for (int rr = 0; rr < 4; ++rr) {
            int row = m0 + mi*16 + q*4 + rr;
            float v = mi ? acc1[rr] : acc0[rr];
            if (col < 256) xcb[(size_t)row*256 + col] = __float2bfloat16(v);
            else           zb[(size_t)row*256 + col - 256] = __float2bfloat16(v);
        }
    }
}

// ---------------- full-K MFMA GEMM (kept for x_proj EPI=2) ------------------
template<int K_, int EPI>
__global__ __launch_bounds__(256) void k_gemmf(
    const __hip_bfloat16* __restrict__ A,
    const __hip_bfloat16* __restrict__ W,
    const float* __restrict__ bias,
    float* __restrict__ Cf, __hip_bfloat16* __restrict__ Cb, int N,
    const float* __restrict__ dpb, __hip_bfloat16* __restrict__ dlt,
    float* __restrict__ Bmo, float* __restrict__ Cmo,
    __hip_bfloat16* __restrict__ Zb)
{
    constexpr int LDT = K_ + 16;
    constexpr int ACH = K_ / 64;
    constexpr int WCH = K_ / 32;
    __shared__ __hip_bfloat16 Al[32][LDT];
    __shared__ __hip_bfloat16 Wl[64][LDT];
    int tid = threadIdx.x;
    int m0 = blockIdx.x * 32, n0 = blockIdx.y * 64;
    const char* gA = (const char*)(A + (size_t)m0 * K_);
    const char* gW = (const char*)(W + (size_t)n0 * K_);
    float4 av[ACH], wv[WCH];
    #pragma unroll
    for (int c = 0; c < ACH; ++c) av[c] = *(const float4*)(gA + c*4096 + tid*16);
    #pragma unroll
    for (int c = 0; c < WCH; ++c) wv[c] = *(const float4*)(gW + c*4096 + tid*16);
    #pragma unroll
    for (int c = 0; c < ACH; ++c) {
        int flat = c*4096 + tid*16;
        *(float4*)&Al[flat / (K_*2)][(flat % (K_*2)) >> 1] = av[c];
    }
    #pragma unroll
    for (int c = 0; c < WCH; ++c) {
        int flat = c*4096 + tid*16;
        *(float4*)&Wl[flat / (K_*2)][(flat % (K_*2)) >> 1] = wv[c];
    }
    __syncthreads();
    int ln = tid & 63, w = tid >> 6;
    int r = ln & 15, q = ln >> 4;
    f32x4 acc0 = (f32x4){0.f,0.f,0.f,0.f};
    f32x4 acc1 = (f32x4){0.f,0.f,0.f,0.f};
    const __hip_bfloat16* wrow  = &Wl[w*16 + r][q*8];
    const __hip_bfloat16* arow0 = &Al[r][q*8];
    const __hip_bfloat16* arow1 = &Al[16 + r][q*8];
    #pragma unroll
    for (int kk = 0; kk < K_/32; ++kk) {
        bf16x8 wf = *(const bf16x8*)(wrow  + kk*32);
        bf16x8 a0 = *(const bf16x8*)(arow0 + kk*32);
        bf16x8 a1 = *(const bf16x8*)(arow1 + kk*32);
        acc0 = __builtin_amdgcn_mfma_f32_16x16x32_bf16(a0, wf, acc0, 0, 0, 0);
        acc1 = __builtin_amdgcn_mfma_f32_16x16x32_bf16(a1, wf, acc1, 0, 0, 0);
    }
    int col = n0 + w*16 + r;
    if (EPI == 2 && col >= 272) return;
    float bv = ((EPI == 0 || EPI == 4) && bias) ? bias[col] : 0.f;
    #pragma unroll
    for (int mi = 0; mi < 2; ++mi) {
        #pragma unroll
        for (int rr = 0; rr < 4; ++rr) {
            int row = m0 + mi*16 + q*4 + rr;
            float v = mi ? acc1[rr] : acc0[rr];
            if (EPI == 2) {
                if (col < 256) {
                    v += dpb[col];
                    v = (v > 20.f) ? v : log1pf(__expf(v));   // softplus
                    dlt[(size_t)row*256 + col] = __float2bfloat16(v);
                } else if (col < 264) {
                    Bmo[(size_t)row*8 + col - 256] = v;
                } else {
                    Cmo[(size_t)row*8 + col - 264] = v;
                }
            } else if (EPI == 3) {
                if (col < 256) Cb[(size_t)row*256 + col] = __float2bfloat16(v);
                else           Zb[(size_t)row*256 + col - 256] = __float2bfloat16(v);
            } else if (EPI == 1) {
                v = v > 0.f ? v : (__expf(v) - 1.f);
                Cb[(size_t)row*N + col] = __float2bfloat16(v);
            } else if (EPI == 4) {
                Cb[(size_t)row*N + col] = __float2bfloat16(v + bv);
            } else {
                v += bv;
                Cf[(size_t)row*N + col] = v;
            }
        }
    }
}

// ---------------- K2: depthwise causal conv(4) + bias + silu (bf16 in/out) ---
__global__ void k_conv(const __hip_bfloat16* __restrict__ xc, const float* __restrict__ cw,
                       const float* __restrict__ cb, __hip_bfloat16* __restrict__ xsb) {
    int idx = blockIdx.x * 256 + threadIdx.x;   // tok*256 + d
    int tok = idx >> 8, d = idx & 255;
    int l = tok & (SEQLEN-1);
    float acc = cb[d];
    #pragma unroll
    for (int j = 0; j < 4; ++j) {
        int lj = l - 3 + j;
        if (lj >= 0) acc = fmaf(cw[d*4+j], __bfloat162float(xc[(size_t)(tok-3+j)*256 + d]), acc);
    }
    acc = acc / (1.f + __expf(-acc));   // silu
    xsb[idx] = __float2bfloat16(acc);
}

// ---------------- K3: chunk-local scan (h_in = 0) -> Ssum + Hend(bf16) -------
__global__ void k_scan1(const __hip_bfloat16* __restrict__ delta,
                        const __hip_bfloat16* __restrict__ xs,
                        const float* __restrict__ Bm, const float* __restrict__ A_log,
                        float* __restrict__ Ssum, unsigned short* __restrict__ Hend) {
    int blk = blockIdx.x;
    int b = blk >> 6, c = blk & 63;
    int d = threadIdx.x;
    int base = b * SEQLEN + c * LCHUNK;
    __shared__ float sB[LCHUNK][8];
    {
        int t2 = threadIdx.x >> 3, j = threadIdx.x & 7;
        sB[t2][j] = Bm[(size_t)(base + t2)*8 + j];
    }
    float A[8];
    #pragma unroll
    for (int n = 0; n < 8; ++n) A[n] = -__expf(A_log[d*8+n]);
    float h[8] = {};
    float S = 0.f;
    __syncthreads();
    const __hip_bfloat16* dptr = delta + (size_t)base*256 + d;
    const __hip_bfloat16* xptr = xs    + (size_t)base*256 + d;
    float dt_c = __bfloat162float(dptr[0]), xt_c = __bfloat162float(xptr[0]);
    for (int t = 0; t < LCHUNK; ++t) {
        float dt_n = 0.f, xt_n = 0.f;
        if (t < LCHUNK-1) {
            dt_n = __bfloat162float(dptr[(t+1)*256]);
            xt_n = __bfloat162float(xptr[(t+1)*256]);
        }
        S += dt_c;
        float dx = dt_c * xt_c;
        #pragma unroll
        for (int n = 0; n < 8; ++n)
            h[n] = fmaf(__expf(A[n]*dt_c), h[n], dx * sB[t][n]);
        dt_c = dt_n; xt_c = xt_n;
    }
    Ssum[(size_t)blk*256 + d] = S;
    u16x8 hp;
    #pragma unroll
    for (int n = 0; n < 8; ++n) hp[n] = f2bf(h[n]);
    *(u16x8*)&Hend[((size_t)blk*256 + d)*8] = hp;
}

// ---------------- K4: chunk combine (bf16 Hend/Hin) --------------------------
__global__ void k_scomb(const float* __restrict__ Ssum, const unsigned short* __restrict__ Hend,
                        const float* __restrict__ A_log, unsigned short* __restrict__ Hin) {
    int blk = blockIdx.x;            // 64 = 8 b x 8 dgrp
    int b = blk >> 3, dg = blk & 7;
    int d = dg*32 + (threadIdx.x >> 3);
    int n = threadIdx.x & 7;
    float A = -__expf(A_log[d*8+n]);
    float h = 0.f;
    size_t i0 = (size_t)(b*NCHUNK)*256 + d;
    float S  = Ssum[i0];
    float He = bf2f(Hend[i0*8 + n]);
    for (int c = 0; c < NCHUNK; ++c) {
        size_t idx = (size_t)(b*NCHUNK + c)*256 + d;
        float Sn = 0.f, Hn = 0.f;
        if (c < NCHUNK-1) {
            size_t ix2 = idx + 256;
            Sn = Ssum[ix2];
            Hn = bf2f(Hend[ix2*8 + n]);
        }
        Hin[idx*8 + n] = f2bf(h);
        h = fmaf(__expf(A*S), h, He);
        S = Sn; He = Hn;
    }
}

// ---------------- K5: final scan; y = (h.C + Dp*xs)*silu(z) -> bf16 yb -------
__global__ void k_scan2(const __hip_bfloat16* __restrict__ delta,
                        const __hip_bfloat16* __restrict__ xs,
                        const float* __restrict__ Bm, const float* __restrict__ Cm,
                        const __hip_bfloat16* __restrict__ zb,
                        const float* __restrict__ A_log,
                        const float* __restrict__ Dp, const unsigned short* __restrict__ Hin,
                        __hip_bfloat16* __restrict__ yb) {
    int blk = blockIdx.x;
    int b = blk >> 6, c = blk & 63;
    int d = threadIdx.x;
    int base = b * SEQLEN + c * LCHUNK;
    __shared__ float sB[LCHUNK][8], sC[LCHUNK][8];
    {
        int t2 = threadIdx.x >> 3, j = threadIdx.x & 7;
        sB[t2][j] = Bm[(size_t)(base + t2)*8 + j];
        sC[t2][j] = Cm[(size_t)(base + t2)*8 + j];
    }
    float A[8], h[8];
    u16x8 hv = *(const u16x8*)&Hin[((size_t)blk*256 + d)*8];
    #pragma unroll
    for (int n = 0; n < 8; ++n) {
        A[n] = -__expf(A_log[d*8+n]);
        h[n] = bf2f(hv[n]);
    }
    float Dpd = Dp[d];
    __syncthreads();
    const __hip_bfloat16* dptr = delta + (size_t)base*256 + d;
    const __hip_bfloat16* xptr = xs    + (size_t)base*256 + d;
    const __hip_bfloat16* zptr = zb    + (size_t)base*256 + d;
    __hip_bfloat16* yptr = yb + (size_t)base*256 + d;
    float dt_c = __bfloat162float(dptr[0]), xt_c = __bfloat162float(xptr[0]);
    for (int t = 0; t < LCHUNK; ++t) {
        float dt_n = 0.f, xt_n = 0.f;
        if (t < LCHUNK-1) {
            dt_n = __bfloat162float(dptr[(t+1)*256]);
            xt_n = __bfloat162float(xptr[(t+1)*256]);
        }
        float dx = dt_c * xt_c;
        float yv = 0.f;
        #pragma unroll
        for (int n = 0; n < 8; ++n) {
            h[n] = fmaf(__expf(A[n]*dt_c), h[n], dx * sB[t][n]);
            yv = fmaf(h[n], sC[t][n], yv);
        }
        yv = fmaf(Dpd, xt_c, yv);
        float z = __bfloat162float(zptr[t*256]);
        yv *= z / (1.f + __expf(-z));
        yptr[t*256] = __float2bfloat16(yv);
        dt_c = dt_n; xt_c = xt_n;
    }
}

// ---------------- K6: fused out_proj+elu -> mlin+bias -> tail -> out ---------
// One block = 32 tokens. Both GEMMs via MFMA; B-fragments direct from L2-hot
// bf16 weights; op/mo never touch HBM.
__global__ __launch_bounds__(256) void k_fin(
    const __hip_bfloat16* __restrict__ yb,
    const __hip_bfloat16* __restrict__ Wo,    // [128][256] bf16
    const __hip_bfloat16* __restrict__ Wm,    // [128][128] bf16
    const float* __restrict__ mlb,
    const float* __restrict__ x,
    const float* __restrict__ p1w, const float* __restrict__ p1b,
    const float* __restrict__ l1w, const float* __restrict__ l1b,
    const float* __restrict__ p2w, const float* __restrict__ p2b,
    float* __restrict__ out)
{
    __shared__ __hip_bfloat16 Al[32][272];
    __shared__ __hip_bfloat16 opl[32][136];
    __shared__ float mol[32][132];
    __shared__ float s_p1w[32][132];
    __shared__ float s_l1w[32][36];
    __shared__ float s_p2w[5][164];
    __shared__ float s_h1[32][36];
    __shared__ float s_o32[32][36];
    __shared__ float s_o[32][6];
    int tid = threadIdx.x;
    int tok0 = blockIdx.x * 32;

    // stage yb tile (32x256 bf16) + tail weights
    const char* gA = (const char*)(yb + (size_t)tok0 * 256);
    float4 av[4];
    #pragma unroll
    for (int c = 0; c < 4; ++c) av[c] = *(const float4*)(gA + c*4096 + tid*16);
    #pragma unroll
    for (int c = 0; c < 4; ++c) {
        int flat = c*4096 + tid*16;
        *(float4*)&Al[flat >> 9][(flat & 511) >> 1] = av[c];
    }
    for (int i = tid; i < 32*32; i += 256) {
        int r2 = i >> 5, c2 = (i & 31) * 4;
        *(float4*)&s_p1w[r2][c2] = *(const float4*)&p1w[r2*128 + c2];
    }
    {
        int r2 = tid >> 3, c2 = (tid & 7) * 4;
        *(float4*)&s_l1w[r2][c2] = *(const float4*)&l1w[r2*32 + c2];
    }
    for (int i = tid; i < 5*163; i += 256) s_p2w[i/163][i%163] = p2w[i];
    __syncthreads();

    int ln = tid & 63, w = tid >> 6;
    int r = ln & 15, q = ln >> 4;
    int c0 = w*16 + r, c1 = c0 + 64;

    // GEMM1: op = elu(yb @ Wo^T), K=256
    f32x4 a00 = (f32x4){0.f,0.f,0.f,0.f};
    f32x4 a01 = a00, a10 = a00, a11 = a00;
    const __hip_bfloat16* b0p = Wo + (size_t)c0*256 + q*8;
    const __hip_bfloat16* b1p = Wo + (size_t)c1*256 + q*8;
    const __hip_bfloat16* a0p = &Al[r][q*8];
    const __hip_bfloat16* a1p = &Al[16+r][q*8];
    #pragma unroll
    for (int kk = 0; kk < 8; ++kk) {
        bf16x8 af0 = *(const bf16x8*)(a0p + kk*32);
        bf16x8 af1 = *(const bf16x8*)(a1p + kk*32);
        bf16x8 bf0 = *(const bf16x8*)(b0p + kk*32);
        bf16x8 bf1 = *(const bf16x8*)(b1p + kk*32);
        a00 = mfma16(af0, bf0, a00);
        a10 = mfma16(af1, bf0, a10);
        a01 = mfma16(af0, bf1, a01);
        a11 = mfma16(af1, bf1, a11);
    }
    #pragma unroll
    for (int rr = 0; rr < 4; ++rr) {
        int row = q*4 + rr;
        float v;
        v = a00[rr]; v = v > 0.f ? v : (__expf(v)-1.f); opl[row][c0]    = __float2bfloat16(v);
        v = a01[rr]; v = v > 0.f ? v : (__expf(v)-1.f); opl[row][c1]    = __float2bfloat16(v);
        v = a10[rr]; v = v > 0.f ? v : (__expf(v)-1.f); opl[row+16][c0] = __float2bfloat16(v);
        v = a11[rr]; v = v > 0.f ? v : (__expf(v)-1.f); opl[row+16][c1] = __float2bfloat16(v);
    }
    __syncthreads();

    // GEMM2: mo = op @ Wm^T + mlb, K=128 (f32 result kept in LDS)
    f32x4 m00 = (f32x4){0.f,0.f,0.f,0.f};
    f32x4 m01 = m00, m10 = m00, m11 = m00;
    const __hip_bfloat16* B0m = Wm + (size_t)c0*128 + q*8;
    const __hip_bfloat16* B1m = Wm + (size_t)c1*128 + q*8;
    const __hip_bfloat16* A0m = &opl[r][q*8];
    const __hip_bfloat16* A1m = &opl[16+r][q*8];
    #pragma unroll
    for (int kk = 0; kk < 4; ++kk) {
        bf16x8 af0 = *(const bf16x8*)(A0m + kk*32);
        bf16x8 af1 = *(const bf16x8*)(A1m + kk*32);
        bf16x8 bf0 = *(const bf16x8*)(B0m + kk*32);
        bf16x8 bf1 = *(const bf16x8*)(B1m + kk*32);
        m00 = mfma16(af0, bf0, m00);
        m10 = mfma16(af1, bf0, m10);
        m01 = mfma16(af0, bf1, m01);
        m11 = mfma16(af1, bf1, m11);
    }
    {
        float bl0 = mlb[c0], bl1 = mlb[c1];
        #pragma unroll
        for (int rr = 0; rr < 4; ++rr) {
            int row = q*4 + rr;
            mol[row][c0]    = m00[rr] + bl0;
            mol[row][c1]    = m01[rr] + bl1;
            mol[row+16][c0] = m10[rr] + bl0;
            mol[row+16][c1] = m11[rr] + bl1;
        }
    }
    __syncthreads();

    // tail: h1 = elu(mo @ p1w^T + p1b)
    {
        int j = tid & 31, tb = tid >> 5;
        float bj = p1b[j];
        #pragma unroll
        for (int p = 0; p < 4; ++p) {
            int tk = tb + p*8;
            float v = bj;
            #pragma unroll 8
            for (int k = 0; k < 128; k += 4) {
                float4 m4 = *(const float4*)&mol[tk][k];
                float4 w4 = *(const float4*)&s_p1w[j][k];
                v = fmaf(m4.x, w4.x, v); v = fmaf(m4.y, w4.y, v);
                v = fmaf(m4.z, w4.z, v); v = fmaf(m4.w, w4.w, v);
            }
            v = v > 0.f ? v : (__expf(v) - 1.f);
            s_h1[tk][j] = v;
        }
    }
    __syncthreads();
    // o32 = h1 @ l1w^T + l1b
    {
        int j = tid & 31, tb = tid >> 5;
        float bj = l1b[j];
        #pragma unroll
        for (int p = 0; p < 4; ++p) {
            int tk = tb + p*8;
            float v = bj;
            #pragma unroll
            for (int k = 0; k < 32; k += 4) {
                float4 m4 = *(const float4*)&s_h1[tk][k];
                float4 w4 = *(const float4*)&s_l1w[j][k];
                v = fmaf(m4.x, w4.x, v); v = fmaf(m4.y, w4.y, v);
                v = fmaf(m4.z, w4.z, v); v = fmaf(m4.w, w4.w, v);
            }
            s_o32[tk][j] = v;
        }
    }
    __syncthreads();
    // proj2 + sin transform: one thread per (token, output j)
    if (tid < 160) {
        int tk = tid / 5, j = tid % 5;
        const float* wr = s_p2w[j];
        int tok = tok0 + tk;
        float v = fmaf(x[tok*3+0], wr[0], 0.f);
        v = fmaf(x[tok*3+1], wr[1], v);
        v = fmaf(x[tok*3+2], wr[2], v);
        #pragma unroll 8
        for (int k = 0; k < 128; ++k) v = fmaf(mol[tk][k], wr[3+k], v);
        #pragma unroll 8
        for (int k = 0; k < 32; ++k)  v = fmaf(s_o32[tk][k], wr[131+k], v);
        v += p2b[j];
        const float PI = 3.14159265358979323846f;
        v = v + __sinf(v*PI)*0.5f;
        v = v + __sinf(v*PI)*0.5f;
        v = (v + 1.f)*0.5f;
        if (j >= 2) v += 1.f;
        s_o[tk][j] = v;
    }
    __syncthreads();
    if (tid < 96) {
        int tk = tid / 3, lnn = tid % 3;
        int tok = tok0 + tk;
        float x0 = x[tok*3+0], x1 = x[tok*3+1], x2 = x[tok*3+2];
        float rv;
        if (lnn == 0)      rv = x0 + s_o[tk][0];
        else if (lnn == 1) rv = x1 + x2*(s_o[tk][1]/s_o[tk][2]);
        else               rv = x2*(s_o[tk][3]/s_o[tk][4]);
        out[(size_t)tok*3 + lnn] = rv;
    }
}

extern "C" void kernel_launch(void* const* d_in, const int* in_sizes, int n_in,
                              void* d_out, int out_size, void* d_ws, size_t ws_size,
                              hipStream_t stream) {
    const float* x        = (const float*)d_in[0];
    const float* proj0_w  = (const float*)d_in[1];
    const float* proj0_b  = (const float*)d_in[2];
    const float* in_proj_w= (const float*)d_in[3];
    const float* conv_w   = (const float*)d_in[4];
    const float* conv_b   = (const float*)d_in[5];
    const float* x_proj_w = (const float*)d_in[6];
    const float* dt_proj_w= (const float*)d_in[7];
    const float* dt_proj_b= (const float*)d_in[8];
    const float* A_log    = (const float*)d_in[9];
    const float* Dp       = (const float*)d_in[10];
    const float* out_proj_w=(const float*)d_in[11];
    const float* mlin_w   = (const float*)d_in[12];
    const float* mlin_b   = (const float*)d_in[13];
    const float* proj1_w  = (const float*)d_in[14];
    const float* proj1_b  = (const float*)d_in[15];
    const float* lin1_w   = (const float*)d_in[16];
    const float* lin1_b   = (const float*)d_in[17];
    const float* proj2_w  = (const float*)d_in[18];
    const float* proj2_b  = (const float*)d_in[19];
    float* out = (float*)d_out;

    char* wsb = (char*)d_ws;
    const size_t MB = 1048576;
    __hip_bfloat16* xc_bf  = (__hip_bfloat16*)(wsb + 4*MB);          // 8 MiB [4,12)
    __hip_bfloat16* z_bf   = (__hip_bfloat16*)(wsb + 12*MB);         // 8 MiB [12,20)
    __hip_bfloat16* xs_bf  = (__hip_bfloat16*)(wsb + 20*MB);         // 8 MiB [20,28)
    __hip_bfloat16* dlt_bf = (__hip_bfloat16*)(wsb + 28*MB);         // 8 MiB [28,36)
    float* Bm   = (float*)(wsb + 36*MB);                             // .5 MiB
    float* Cm   = (float*)(wsb + 36*MB + 524288);                    // .5 MiB
    float* Ssum = (float*)(wsb + 37*MB);                             // .5 MiB
    unsigned short* Hend = (unsigned short*)(wsb + 37*MB + 524288);  // 2 MiB [37.5,39.5)
    unsigned short* Hin  = (unsigned short*)(wsb + 39*MB + 524288);  // 2 MiB [39.5,41.5)
    __hip_bfloat16* yb = (__hip_bfloat16*)(wsb + 41*MB + 524288);    // 8 MiB [41.5,49.5)
    __hip_bfloat16* w_in_bf  = (__hip_bfloat16*)(wsb + 50*MB);             // 128K
    __hip_bfloat16* w_out_bf = (__hip_bfloat16*)(wsb + 50*MB + 131072);    // 64K
    __hip_bfloat16* w_ml_bf  = (__hip_bfloat16*)(wsb + 50*MB + 196608);    // 32K
    __hip_bfloat16* Wx_bf    = (__hip_bfloat16*)(wsb + 50*MB + 229376);    // 192K

    // K0: weight prep (bf16 conversions + fused x_proj/dt_proj weight)
    k_prep2<<<832, 256, 0, stream>>>(in_proj_w, out_proj_w, mlin_w, x_proj_w,
                                     dt_proj_w, w_in_bf, w_out_bf, w_ml_bf, Wx_bf);
    // K1: fused proj0+tanh+in_proj (M=16384,N=512,K=128) -> split xc_bf / z_bf
    k_gemm_in<<<dim3(TOKENS/32, 8), 256, 0, stream>>>(
        x, proj0_w, proj0_b, w_in_bf, xc_bf, z_bf);
    // K2: conv -> xs_bf
    k_conv<<<TOKENS, 256, 0, stream>>>(xc_bf, conv_w, conv_b, xs_bf);
    // K3: fused x_proj + dt_proj + softplus
    k_gemmf<256,2><<<dim3(TOKENS/32, 5), 256, 0, stream>>>(
        xs_bf, Wx_bf, nullptr, nullptr, nullptr, 384, dt_proj_b, dlt_bf, Bm, Cm, nullptr);
    // K4-K6: scans
    k_scan1<<<8*NCHUNK, 256, 0, stream>>>(dlt_bf, xs_bf, Bm, A_log, Ssum, Hend);
    k_scomb<<<64, 256, 0, stream>>>(Ssum, Hend, A_log, Hin);
    k_scan2<<<8*NCHUNK, 256, 0, stream>>>(dlt_bf, xs_bf, Bm, Cm, z_bf, A_log, Dp, Hin, yb);
    // K7: fused out_proj+elu + mlin + tail -> out
    k_fin<<<TOKENS/32, 256, 0, stream>>>(yb, w_out_bf, w_ml_bf, mlin_b, x,
                                         proj1_w, proj1_b, lin1_w, lin1_b,
                                         proj2_w, proj2_b, out);
}